// Round 4
// baseline (311.495 us; speedup 1.0000x reference)
//
#include <hip/hip_runtime.h>
#include <stdint.h>
#include <stddef.h>

typedef _Float16 f16;
typedef __attribute__((ext_vector_type(8))) _Float16 f16x8;
typedef __attribute__((ext_vector_type(4))) float f32x4;

#define GPTR(p) ((const __attribute__((address_space(1))) void*)(p))
#define LPTR(p) ((__attribute__((address_space(3))) void*)(p))

// async global->LDS, 16B per lane; LDS dest = wave-uniform base + lane*16
__device__ __forceinline__ void async16(const void* g, void* l) {
    __builtin_amdgcn_global_load_lds(GPTR(g), LPTR(l), 16, 0, 0);
}

// ---------------------------------------------------------------------------
// Sparsify (2:4 soft-threshold along last dim of W[K][M]) * scale -> fp16,
// stored in MFMA-fragment order: 16B block idx =
//   ((k>>5)*(M/16) + (col>>4))*64 + ((k>>3)&3)*16 + (col&15),  elem e = k&7.
// A wave's B-fragment read = wave-uniform base + lane*16 (coalesced 1KB).
// ---------------------------------------------------------------------------
__global__ __launch_bounds__(256) void sparsify_frag(
        const float* __restrict__ W, const float* __restrict__ scale,
        f16* __restrict__ Wf, int K, int M) {
    __shared__ f16 T[64][80];
    const int r0 = blockIdx.y << 6, m0 = blockIdx.x << 6;   // r0: k-dim, m0: col
    const float s = scale[0];
    const int t = threadIdx.x;
    const int rr = t >> 2, mb = (t & 3) << 4;
    const float* src = W + (size_t)(r0 + rr) * M + m0 + mb;
    #pragma unroll
    for (int j = 0; j < 4; j++) {
        float4 v = *(const float4*)(src + j * 4);
        float a0 = fabsf(v.x), a1 = fabsf(v.y), a2 = fabsf(v.z), a3 = fabsf(v.w);
        float lo1 = fminf(a0, a1), hi1 = fmaxf(a0, a1);
        float lo2 = fminf(a2, a3), hi2 = fmaxf(a2, a3);
        float th = fminf(fmaxf(lo1, lo2), fminf(hi1, hi2));
        int m = mb + j * 4;
        T[m + 0][rr] = (f16)(copysignf(fmaxf(a0 - th, 0.f), v.x) * s);
        T[m + 1][rr] = (f16)(copysignf(fmaxf(a1 - th, 0.f), v.y) * s);
        T[m + 2][rr] = (f16)(copysignf(fmaxf(a2 - th, 0.f), v.z) * s);
        T[m + 3][rr] = (f16)(copysignf(fmaxf(a3 - th, 0.f), v.w) * s);
    }
    __syncthreads();
    const int mm = t >> 2, rb = (t & 3) << 4;
    const int col = m0 + mm;
    const int Mb = M >> 4;
    #pragma unroll
    for (int h = 0; h < 2; h++) {
        int k = r0 + rb + h * 8;
        size_t blk = ((size_t)(k >> 5) * Mb + (col >> 4)) * 64
                   + (size_t)(((k >> 3) & 3) * 16 + (col & 15));
        *(f16x8*)(Wf + blk * 8) = *(const f16x8*)&T[mm][rb + h * 8];
    }
}

// ---------------------------------------------------------------------------
// GEMM1: Hf = fp16(x[16384][2048]) @ W1f + b1   (Hf in fragment order)
// BM=64 BN=64 BK=64, 256 thr (2x2 waves of 32x32), 1024 blocks = 4/CU,
// XCD-paired col-blocks (A panel L2-local).
// A: reg-staged f32->f16 (RNE) into fragment-order LDS [ks][rg][lane] --
//    every LDS write/read is the linear lane*16 pattern: conflict-free,
//    f16 (half the LDS bytes of round 3), no in-loop cvt/repack.
// B: NO LDS -- fragment-order Bf read directly as coalesced 1KB wave loads
//    (B = 1 MB, L2/L3-hot).
// ---------------------------------------------------------------------------
__global__ __launch_bounds__(256, 4) void gemm1_kernel(
        const float* __restrict__ A, const f16* __restrict__ Bf,
        const float* __restrict__ bias, f16* __restrict__ Hf) {
    constexpr int K = 2048, BK = 64, NT = K / BK;
    __shared__ f16x8 Ash[512];   // 8 KB: [ks(2)][rowgrp(4)][lane(64)]

    const int tid = threadIdx.x, lane = tid & 63, wv = tid >> 6;
    const int wm = wv & 1, wn = wv >> 1;
    const int lr = lane & 15, q = lane >> 4;

    // XCD pairing: 4 col-blocks of row-panel p get ids == p (mod 8)
    const int id = blockIdx.x + (blockIdx.y << 2);
    const int xr = id & 7, xt = id >> 3;
    const int nb = xt & 3, p = xr + ((xt >> 2) << 3);
    const int row0 = p << 6, col0 = nb << 6;

    f32x4 acc[2][2] = {};

    // A staging: thread owns chunk tid (ks=0) and tid+256 (ks=1).
    // chunk c: lane=c&63 (row off = c&15, k-sub = (c>>4)&3), rowgrp=(c>>6)&3
    const int clr = tid & 15, cq = (tid >> 4) & 3, crg = (tid >> 6) & 3;
    const float* aSrc = A + (size_t)(row0 + crg * 16 + clr) * K + cq * 8;
    // B fragment base for this wave's two n-chunks
    constexpr size_t BKT = (size_t)16 * 64 * 8;   // one kt32 step (Mb = 256/16)
    const f16* bBase = Bf + ((size_t)(col0 >> 4) + wn * 2) * 64 * 8 + lane * 8;

    for (int t = 0; t < NT; ++t) {
        // B direct loads for this K-step (no LDS, coalesced, L2-hot)
        const f16* bp = bBase + (size_t)(2 * t) * BKT;
        f16x8 bf[2][2];
        bf[0][0] = *(const f16x8*)(bp);
        bf[0][1] = *(const f16x8*)(bp + 64 * 8);
        bf[1][0] = *(const f16x8*)(bp + BKT);
        bf[1][1] = *(const f16x8*)(bp + BKT + 64 * 8);

        // A stage: 4 f32x4 loads -> 16 RNE cvt -> 2 linear ds_write_b128
        float4 v0 = *(const float4*)(aSrc);
        float4 v1 = *(const float4*)(aSrc + 4);
        float4 v2 = *(const float4*)(aSrc + 32);
        float4 v3 = *(const float4*)(aSrc + 36);
        aSrc += BK;
        f16x8 h0, h1;
        h0[0] = (f16)v0.x; h0[1] = (f16)v0.y; h0[2] = (f16)v0.z; h0[3] = (f16)v0.w;
        h0[4] = (f16)v1.x; h0[5] = (f16)v1.y; h0[6] = (f16)v1.z; h0[7] = (f16)v1.w;
        h1[0] = (f16)v2.x; h1[1] = (f16)v2.y; h1[2] = (f16)v2.z; h1[3] = (f16)v2.w;
        h1[4] = (f16)v3.x; h1[5] = (f16)v3.y; h1[6] = (f16)v3.z; h1[7] = (f16)v3.w;
        Ash[tid]       = h0;
        Ash[tid + 256] = h1;
        __syncthreads();

        #pragma unroll
        for (int ks = 0; ks < 2; ks++) {
            f16x8 af[2];
            af[0] = Ash[(ks * 4 + wm * 2 + 0) * 64 + lane];
            af[1] = Ash[(ks * 4 + wm * 2 + 1) * 64 + lane];
            #pragma unroll
            for (int m = 0; m < 2; m++)
                #pragma unroll
                for (int n = 0; n < 2; n++)
                    acc[m][n] = __builtin_amdgcn_mfma_f32_16x16x32_f16(
                        af[m], bf[ks][n], acc[m][n], 0, 0, 0);
        }
        __syncthreads();   // WAR: Ash rewritten next iter
    }

    // epilogue: write H in fragment order (gemm2's A layout, M/16 = 1024)
    #pragma unroll
    for (int m = 0; m < 2; m++) {
        int r16 = (row0 + wm * 32 + m * 16) >> 4;
        #pragma unroll
        for (int n = 0; n < 2; n++) {
            int gc = col0 + wn * 32 + n * 16 + lr;
            float bv = bias[gc];
            int kt = gc >> 5, qq = (gc >> 3) & 3, e = gc & 7;
            f16* hb = Hf + ((((size_t)kt * 1024 + r16) * 4 + qq) * 16) * 8 + e;
            #pragma unroll
            for (int rr = 0; rr < 4; rr++)
                hb[(q * 4 + rr) * 8] = (f16)(acc[m][n][rr] + bv);
        }
    }
}

// ---------------------------------------------------------------------------
// GEMM2: y[16384][2048](f32) = H @ W2f + b2.   BM=128 BN=64 BK=64, NT=4.
// 256 thr (2x2 waves of 64x32), single-buffer 24KB, 4096 blocks = 4/CU.
// Both operands fragment-order: linear staging, conflict-free lane*16 reads.
// (unchanged from round 3 -- verified)
// ---------------------------------------------------------------------------
__global__ __launch_bounds__(256, 4) void gemm2_kernel(
        const f16* __restrict__ Hf, const f16* __restrict__ Bf,
        const float* __restrict__ bias, float* __restrict__ Y) {
    constexpr int N = 2048, NT = 4;
    __shared__ f16x8 As[16 * 64];   // 16 KB  [s*8 + r16][lane]
    __shared__ f16x8 Bs[8 * 64];    //  8 KB  [s*4 + c16][lane]

    const int tid = threadIdx.x, lane = tid & 63, wv = tid >> 6;
    const int wm = wv & 1, wn = wv >> 1;
    const int lr = lane & 15, q = lane >> 4;

    const int id = blockIdx.x + (blockIdx.y << 5);
    const int xr = id & 7, xt = id >> 3;
    const int bx = xt & 31, by = xr + ((xt >> 5) << 3);
    const int row0 = by << 7, col0 = bx << 6;

    f32x4 acc[4][2] = {};

    for (int t = 0; t < NT; ++t) {
        int kt0 = 2 * t;
        #pragma unroll
        for (int j = 0; j < 4; j++) {
            int i = wv * 4 + j;
            int s = i >> 3, rb = i & 7;
            const f16* srcp = Hf + (((size_t)(kt0 + s) * 1024 + (row0 >> 4) + rb) * 64) * 8
                              + lane * 8;
            async16(srcp, (char*)As + i * 1024);
        }
        #pragma unroll
        for (int j = 0; j < 2; j++) {
            int ch = wv * 2 + j;
            int s = ch >> 2, c = ch & 3;
            const f16* srcp = Bf + (((size_t)(kt0 + s) * 128 + (col0 >> 4) + c) * 64) * 8
                              + lane * 8;
            async16(srcp, (char*)Bs + ch * 1024);
        }
        __syncthreads();
        #pragma unroll
        for (int ks = 0; ks < 2; ks++) {
            f16x8 af[4], bf[2];
            #pragma unroll
            for (int m = 0; m < 4; m++)
                af[m] = As[(ks * 8 + wm * 4 + m) * 64 + lane];
            #pragma unroll
            for (int n = 0; n < 2; n++)
                bf[n] = Bs[(ks * 4 + wn * 2 + n) * 64 + lane];
            #pragma unroll
            for (int m = 0; m < 4; m++)
                #pragma unroll
                for (int n = 0; n < 2; n++)
                    acc[m][n] = __builtin_amdgcn_mfma_f32_16x16x32_f16(
                        af[m], bf[n], acc[m][n], 0, 0, 0);
        }
        __syncthreads();
    }

    #pragma unroll
    for (int m = 0; m < 4; m++) {
        int gr0 = row0 + wm * 64 + m * 16 + q * 4;
        #pragma unroll
        for (int n = 0; n < 2; n++) {
            int gc = col0 + wn * 32 + n * 16 + lr;
            float bv = bias[gc];
            #pragma unroll
            for (int rr = 0; rr < 4; rr++)
                Y[(size_t)(gr0 + rr) * N + gc] = acc[m][n][rr] + bv;
        }
    }
}

// ---------------------------------------------------------------------------
// launch
// ---------------------------------------------------------------------------
extern "C" void kernel_launch(void* const* d_in, const int* in_sizes, int n_in,
                              void* d_out, int out_size, void* d_ws, size_t ws_size,
                              hipStream_t stream) {
    const float* x  = (const float*)d_in[0];   // [8,2048,2048]
    const float* w1 = (const float*)d_in[1];   // [2048,256]
    const float* w2 = (const float*)d_in[2];   // [256,2048]
    const float* b1 = (const float*)d_in[3];   // [256]
    const float* b2 = (const float*)d_in[4];   // [2048]
    const float* s1 = (const float*)d_in[5];   // [1]
    const float* s2 = (const float*)d_in[6];   // [1]
    float* y = (float*)d_out;                  // [8,2048,2048] fp32

    constexpr int NROWS = 8 * 2048;  // 16384
    constexpr int D = 2048, R = 256;

    char* ws = (char*)d_ws;
    f16* W1f = (f16*)ws;                   // fragment-order [64][16][4][16][8], 1 MiB
    f16* W2f = (f16*)(ws + (2u << 20));    // fragment-order [8][128][4][16][8], 1 MiB
    f16* Hf  = (f16*)(ws + (4u << 20));    // fragment-order [8][1024][4][16][8], 8 MiB

    hipLaunchKernelGGL(sparsify_frag, dim3(R / 64, D / 64), dim3(256),
                       0, stream, w1, s1, W1f, D, R);
    hipLaunchKernelGGL(sparsify_frag, dim3(D / 64, R / 64), dim3(256),
                       0, stream, w2, s2, W2f, R, D);

    // GEMM1: 4 x 256 = 1024 blocks (4/CU), XCD-paired A-panel sharing
    hipLaunchKernelGGL(gemm1_kernel, dim3(4, NROWS / 64), dim3(256),
                       0, stream, x, W1f, b1, Hf);

    // GEMM2: 32 x 128 = 4096 blocks (4/CU)
    hipLaunchKernelGGL(gemm2_kernel, dim3(D / 64, NROWS / 128), dim3(256),
                       0, stream, Hf, W2f, b2, y);
}